// Round 2
// baseline (618.179 us; speedup 1.0000x reference)
//
#include <hip/hip_runtime.h>
#include <math.h>

#define C_DIM 128
#define H_NUM 8
#define DH_NUM 16
#define NP_NUM 4
#define HD 128   // H*DH
#define PC 32    // H*NP

// ---------------- helpers ----------------
__device__ __forceinline__ float dot4f(float4 a, float4 b){
  return a.x*b.x + a.y*b.y + a.z*b.z + a.w*b.w;
}
__device__ __forceinline__ float4 scale4(float4 a, float s){
  return make_float4(a.x*s, a.y*s, a.z*s, a.w*s);
}
__device__ __forceinline__ float4 fma4(float4 acc, float p, float4 v){
  return make_float4(acc.x + p*v.x, acc.y + p*v.y, acc.z + p*v.z, acc.w + p*v.w);
}
__device__ __forceinline__ float sqdiff4(float4 a, float4 b){
  float dx = a.x - b.x, dy = a.y - b.y, dz = a.z - b.z, dw = a.w - b.w;
  return dx*dx + dy*dy + dz*dz + dw*dw;
}
__device__ __forceinline__ float gelu_exact(float v){
  return 0.5f * v * (1.0f + erff(v * 0.70710678118654752440f));
}
// row-offset modes: 0 -> r*ld ; 1 -> x-like (N,4,C) vector rows: (r/3)*512 + (r%3+1)*128
__device__ __forceinline__ size_t row_off(int mode, int r, int ld){
  if (mode == 0) return (size_t)r * (size_t)ld;
  int n3 = r / 3;
  int xd = r - n3 * 3;
  return (size_t)n3 * 512 + (size_t)(xd + 1) * 128;
}

#define RED4(v, off) { v.x += __shfl_xor(v.x, off); v.y += __shfl_xor(v.y, off); \
                       v.z += __shfl_xor(v.z, off); v.w += __shfl_xor(v.w, off); }

// ---------------- CSR build ----------------
__global__ void count_kernel(const int* __restrict__ ei, int* __restrict__ deg, int E){
  int e = blockIdx.x * blockDim.x + threadIdx.x;
  if (e < E) atomicAdd(&deg[ei[E + e]], 1);
}

__global__ __launch_bounds__(1024) void scan_kernel(const int* __restrict__ deg,
                                                    int* __restrict__ row_start, int n){
  __shared__ int sums[1024];
  int tid = threadIdx.x;
  int chunk = (n + 1023) >> 10;
  int beg = tid * chunk;
  int end = beg + chunk; if (end > n) end = n;
  int s = 0;
  for (int i = beg; i < end; ++i) s += deg[i];
  sums[tid] = s;
  __syncthreads();
  for (int off = 1; off < 1024; off <<= 1){
    int v = (tid >= off) ? sums[tid - off] : 0;
    __syncthreads();
    sums[tid] += v;
    __syncthreads();
  }
  int run = (tid > 0) ? sums[tid - 1] : 0;
  for (int i = beg; i < end; ++i){ row_start[i] = run; run += deg[i]; }
  if (tid == 1023) row_start[n] = sums[1023];
}

__global__ void fill_kernel(const int* __restrict__ ei, const int* __restrict__ row_start,
                            int* __restrict__ cursor, int* __restrict__ csr_src, int E){
  int e = blockIdx.x * blockDim.x + threadIdx.x;
  if (e >= E) return;
  int s = ei[e];
  int d = ei[E + e];
  int pos = atomicAdd(&cursor[d], 1);
  csr_src[row_start[d] + pos] = s;
}

// ---------------- generic fp32 tiled GEMM with fused epilogues ----------------
// epi: 0 none, 1 +rowadd[r], 2 gelu(acc+bias), 3 +bias+resid[coff+c],
//      4 gated residual: resid[coff+c] + acc*sigmoid(gate[(r/3)*256+128+c])
template<int BM, int BN, int BK, int TM, int TN>
__global__ __launch_bounds__(256) void gemm_kernel(
    const float* __restrict__ A, int amode, int lda, const float* __restrict__ subrow,
    const float* __restrict__ B, int ldb,
    float* __restrict__ C, int cmode, int ldc,
    const float* __restrict__ bias, const float* __restrict__ rowadd,
    const float* __restrict__ resid, const float* __restrict__ gate,
    int M, int K, int Nc, int epi)
{
  __shared__ float As[BK][BM + 1];
  __shared__ float Bs[BK][BN + 1];
  constexpr int TX = BN / TN;
  const int tid = threadIdx.x;
  const int tx = tid % TX;
  const int ty = tid / TX;
  const int rb = blockIdx.x * BM;
  const int cb = blockIdx.y * BN;

  float acc[TM][TN];
  #pragma unroll
  for (int u = 0; u < TM; ++u)
    #pragma unroll
    for (int v = 0; v < TN; ++v) acc[u][v] = 0.f;

  for (int k0 = 0; k0 < K; k0 += BK){
    constexpr int AEL = BM * BK / 256;
    #pragma unroll
    for (int i = 0; i < AEL; ++i){
      int lin = tid + i * 256;
      int r = lin / BK;
      int kk = lin % BK;
      int row = rb + r;
      float v = 0.f;
      if (row < M){
        v = A[row_off(amode, row, lda) + (size_t)(k0 + kk)];
        if (subrow) v -= subrow[row];
      }
      As[kk][r] = v;
    }
    constexpr int BEL = BK * BN / 256;
    #pragma unroll
    for (int i = 0; i < BEL; ++i){
      int lin = tid + i * 256;
      int kk = lin / BN;
      int c = lin % BN;
      int col = cb + c;
      float v = 0.f;
      if (col < Nc) v = B[(size_t)(k0 + kk) * ldb + col];
      Bs[kk][c] = v;
    }
    __syncthreads();
    #pragma unroll
    for (int kk = 0; kk < BK; ++kk){
      float a[TM], b[TN];
      #pragma unroll
      for (int u = 0; u < TM; ++u) a[u] = As[kk][ty * TM + u];
      #pragma unroll
      for (int v = 0; v < TN; ++v) b[v] = Bs[kk][tx * TN + v];
      #pragma unroll
      for (int u = 0; u < TM; ++u)
        #pragma unroll
        for (int v = 0; v < TN; ++v) acc[u][v] += a[u] * b[v];
    }
    __syncthreads();
  }

  #pragma unroll
  for (int u = 0; u < TM; ++u){
    int r = rb + ty * TM + u;
    if (r >= M) continue;
    size_t coff = row_off(cmode, r, ldc);
    #pragma unroll
    for (int v = 0; v < TN; ++v){
      int c = cb + tx * TN + v;
      if (c >= Nc) continue;
      float val = acc[u][v];
      if (bias) val += bias[c];
      if (epi == 1) val += rowadd[r];
      else if (epi == 2) val = gelu_exact(val);
      else if (epi == 3) val += resid[coff + c];
      else if (epi == 4){
        float gt = 1.f / (1.f + expf(-gate[(size_t)(r / 3) * 256 + 128 + c]));
        val = resid[coff + c] + val * gt;
      }
      C[coff + c] = val;
    }
  }
}

// ---------------- per-node online-softmax attention over CSR ----------------
// One wave (64 lanes) per node: 8 edge-slots (g) x 8 heads (h).
__global__ __launch_bounds__(64) void attn_kernel(
    const float* __restrict__ Q, const float* __restrict__ Kmat,
    const float* __restrict__ Vmat, const float* __restrict__ Qp,
    const float* __restrict__ Kp, const float* __restrict__ Vp,
    const float* __restrict__ gamma,
    const int* __restrict__ row_start, const int* __restrict__ csr_src,
    float* __restrict__ agg_s, float* __restrict__ agg_p, int n)
{
  const int node = blockIdx.x;
  if (node >= n) return;
  const int lane = threadIdx.x;
  const int g = lane >> 3;
  const int h = lane & 7;

  const float4* q4 = (const float4*)(Q + (size_t)node * HD + h * DH_NUM);
  const float4 qa = q4[0], qb = q4[1], qc = q4[2], qd = q4[3];
  const float4 qp0 = *(const float4*)(Qp + ((size_t)node * 3 + 0) * PC + h * 4);
  const float4 qp1 = *(const float4*)(Qp + ((size_t)node * 3 + 1) * PC + h * 4);
  const float4 qp2 = *(const float4*)(Qp + ((size_t)node * 3 + 2) * PC + h * 4);
  const float c05 = 0.5f * log1pf(expf(gamma[h]));

  const int e0 = row_start[node], e1 = row_start[node + 1];

  float m_run = -INFINITY;
  float zacc = 0.f;
  float4 as0 = make_float4(0,0,0,0), as1 = as0, as2 = as0, as3 = as0;
  float4 ap0 = as0, ap1 = as0, ap2 = as0;

  for (int base = e0; base < e1; base += 8){
    const int e = base + g;
    const bool valid = (e < e1);
    const int src = valid ? csr_src[e] : 0;

    const float4* k4 = (const float4*)(Kmat + (size_t)src * HD + h * DH_NUM);
    float dot = dot4f(qa, k4[0]) + dot4f(qb, k4[1]) + dot4f(qc, k4[2]) + dot4f(qd, k4[3]);
    const float4 kp0 = *(const float4*)(Kp + ((size_t)src * 3 + 0) * PC + h * 4);
    const float4 kp1 = *(const float4*)(Kp + ((size_t)src * 3 + 1) * PC + h * 4);
    const float4 kp2 = *(const float4*)(Kp + ((size_t)src * 3 + 2) * PC + h * 4);
    float pd = sqdiff4(qp0, kp0) + sqdiff4(qp1, kp1) + sqdiff4(qp2, kp2);
    float logit = valid ? (dot * 0.25f - c05 * pd) : -INFINITY;

    // tile max across the 8 edge slots (lanes differing in bits 3..5, same head)
    float tmax = logit;
    tmax = fmaxf(tmax, __shfl_xor(tmax, 8));
    tmax = fmaxf(tmax, __shfl_xor(tmax, 16));
    tmax = fmaxf(tmax, __shfl_xor(tmax, 32));
    float m_new = fmaxf(m_run, tmax);
    float sc = expf(m_run - m_new);    // exp(-inf)=0 on first iter
    float pe = valid ? expf(logit - m_new) : 0.f;
    m_run = m_new;

    const float4* v4 = (const float4*)(Vmat + (size_t)src * HD + h * DH_NUM);
    const float4 vv0 = v4[0], vv1 = v4[1], vv2 = v4[2], vv3 = v4[3];
    const float4 vp0 = *(const float4*)(Vp + ((size_t)src * 3 + 0) * PC + h * 4);
    const float4 vp1 = *(const float4*)(Vp + ((size_t)src * 3 + 1) * PC + h * 4);
    const float4 vp2 = *(const float4*)(Vp + ((size_t)src * 3 + 2) * PC + h * 4);

    zacc = zacc * sc + pe;
    as0 = fma4(scale4(as0, sc), pe, vv0);
    as1 = fma4(scale4(as1, sc), pe, vv1);
    as2 = fma4(scale4(as2, sc), pe, vv2);
    as3 = fma4(scale4(as3, sc), pe, vv3);
    ap0 = fma4(scale4(ap0, sc), pe, vp0);
    ap1 = fma4(scale4(ap1, sc), pe, vp1);
    ap2 = fma4(scale4(ap2, sc), pe, vp2);
  }

  // reduce across the 8 edge slots (all lanes of a head share identical m_run)
  for (int off = 8; off < 64; off <<= 1){
    zacc += __shfl_xor(zacc, off);
    RED4(as0, off); RED4(as1, off); RED4(as2, off); RED4(as3, off);
    RED4(ap0, off); RED4(ap1, off); RED4(ap2, off);
  }
  float inv = 1.f / (zacc + 1e-9f);
  if (g == 0){
    float4* o = (float4*)(agg_s + (size_t)node * HD + h * DH_NUM);
    o[0] = scale4(as0, inv); o[1] = scale4(as1, inv);
    o[2] = scale4(as2, inv); o[3] = scale4(as3, inv);
    *(float4*)(agg_p + ((size_t)node * 3 + 0) * PC + h * 4) = scale4(ap0, inv);
    *(float4*)(agg_p + ((size_t)node * 3 + 1) * PC + h * 4) = scale4(ap1, inv);
    *(float4*)(agg_p + ((size_t)node * 3 + 2) * PC + h * 4) = scale4(ap2, inv);
  }
}

// ---------------- small glue kernels ----------------
__global__ void norm_kernel(const float* __restrict__ xm, float* __restrict__ x1, int n){
  int i = blockIdx.x * blockDim.x + threadIdx.x;
  if (i >= n * 128) return;
  int node = i >> 7, c = i & 127;
  const float* b = xm + (size_t)node * 512;
  float v1 = b[128 + c], v2 = b[256 + c], v3 = b[384 + c];
  x1[(size_t)node * 256 + c] = b[c];
  x1[(size_t)node * 256 + 128 + c] = sqrtf(v1*v1 + v2*v2 + v3*v3 + 1e-4f);
}

__global__ void out_scalar_kernel(const float* __restrict__ xm, const float* __restrict__ y,
                                  float* __restrict__ out, int n){
  int i = blockIdx.x * blockDim.x + threadIdx.x;
  if (i >= n * 128) return;
  int node = i >> 7, c = i & 127;
  out[(size_t)node * 512 + c] = xm[(size_t)node * 512 + c] + y[(size_t)node * 256 + c];
}

// ---------------- launch ----------------
extern "C" void kernel_launch(void* const* d_in, const int* in_sizes, int n_in,
                              void* d_out, int out_size, void* d_ws, size_t ws_size,
                              hipStream_t stream)
{
  const float* x      = (const float*)d_in[0];
  const int*   ei     = (const int*)d_in[1];
  const float* t      = (const float*)d_in[2];
  const float* Wq     = (const float*)d_in[3];
  const float* Wk     = (const float*)d_in[4];
  const float* Wv     = (const float*)d_in[5];
  const float* Wq_pts = (const float*)d_in[6];
  const float* Wk_pts = (const float*)d_in[7];
  const float* Wv_pts = (const float*)d_in[8];
  const float* gamma  = (const float*)d_in[9];
  const float* Wo_s   = (const float*)d_in[10];
  const float* bo_s   = (const float*)d_in[11];
  const float* Wo_pts = (const float*)d_in[12];
  const float* W1     = (const float*)d_in[13];
  const float* b1     = (const float*)d_in[14];
  const float* W2     = (const float*)d_in[15];
  const float* b2     = (const float*)d_in[16];
  const float* Wl     = (const float*)d_in[17];
  float* out = (float*)d_out;

  const int n = in_sizes[0] / 512;
  const int E = in_sizes[1] / 2;

  float* ws = (float*)d_ws;
  // float regions (elements)
  size_t q_off   = 0;
  size_t k_off   = (size_t)n * HD;
  size_t v_off   = (size_t)n * HD * 2;
  size_t qp_off  = (size_t)n * HD * 3;
  size_t kp_off  = qp_off + (size_t)n * 3 * PC;
  size_t vp_off  = kp_off + (size_t)n * 3 * PC;
  size_t proj_end = vp_off + (size_t)n * 3 * PC;     // n*672
  size_t aggs_off = proj_end;
  size_t aggp_off = aggs_off + (size_t)n * HD;
  size_t agg_end  = aggp_off + (size_t)n * 3 * PC;   // n*896
  size_t x1_off   = agg_end;                          // n*256
  size_t f_end    = x1_off + (size_t)n * 256;         // n*1152
  // reuse dead projection region for MLP buffers (proj region = n*672 >= n*512)
  size_t h_off = 0;
  size_t y_off = (size_t)n * 256;

  int* ibase     = (int*)(ws + f_end);
  int* deg       = ibase;
  int* cursor    = deg + n;
  int* row_start = cursor + n;
  int* csr_src   = row_start + (n + 1);

  // CSR build
  hipMemsetAsync(deg, 0, sizeof(int) * (size_t)(2 * n), stream);
  count_kernel<<<(E + 255) / 256, 256, 0, stream>>>(ei, deg, E);
  scan_kernel<<<1, 1024, 0, stream>>>(deg, row_start, n);
  fill_kernel<<<(E + 255) / 256, 256, 0, stream>>>(ei, row_start, cursor, csr_src, E);

  auto g64 = [&](const float* A, int amode, int lda, const float* subrow,
                 const float* B, int ldb, float* Cp, int cmode, int ldc,
                 const float* bias, const float* rowadd, const float* resid,
                 const float* gate, int M, int K, int Nc, int epi){
    dim3 grid((M + 63) / 64, (Nc + 63) / 64);
    gemm_kernel<64,64,32,4,4><<<grid, 256, 0, stream>>>(
        A, amode, lda, subrow, B, ldb, Cp, cmode, ldc,
        bias, rowadd, resid, gate, M, K, Nc, epi);
  };

  // projections
  g64(x, 0, 512, nullptr, Wq,     HD, ws + q_off,  0, HD, nullptr, nullptr, nullptr, nullptr, n,   C_DIM, HD, 0);
  g64(x, 0, 512, nullptr, Wk,     HD, ws + k_off,  0, HD, nullptr, nullptr, nullptr, nullptr, n,   C_DIM, HD, 0);
  g64(x, 0, 512, nullptr, Wv,     HD, ws + v_off,  0, HD, nullptr, nullptr, nullptr, nullptr, n,   C_DIM, HD, 0);
  g64(x, 1, 0,   nullptr, Wq_pts, PC, ws + qp_off, 0, PC, nullptr, t,       nullptr, nullptr, 3*n, C_DIM, PC, 1);
  g64(x, 1, 0,   nullptr, Wk_pts, PC, ws + kp_off, 0, PC, nullptr, t,       nullptr, nullptr, 3*n, C_DIM, PC, 1);
  g64(x, 1, 0,   nullptr, Wv_pts, PC, ws + vp_off, 0, PC, nullptr, t,       nullptr, nullptr, 3*n, C_DIM, PC, 1);

  // attention
  attn_kernel<<<n, 64, 0, stream>>>(ws + q_off, ws + k_off, ws + v_off,
                                    ws + qp_off, ws + kp_off, ws + vp_off,
                                    gamma, row_start, csr_src,
                                    ws + aggs_off, ws + aggp_off, n);

  // x_mid lives in d_out (residual-add fused)
  float* xmid = out;
  g64(ws + aggs_off, 0, HD, nullptr, Wo_s,   C_DIM, xmid, 0, 512, bo_s,    nullptr, x, nullptr, n,   HD, C_DIM, 3);
  g64(ws + aggp_off, 0, PC, t,       Wo_pts, C_DIM, xmid, 1, 0,   nullptr, nullptr, x, nullptr, 3*n, PC, C_DIM, 3);

  // norm -> x1
  norm_kernel<<<(n * 128 + 255) / 256, 256, 0, stream>>>(xmid, ws + x1_off, n);

  // MLP
  g64(ws + x1_off, 0, 256, nullptr, W1, 256, ws + h_off, 0, 256, b1, nullptr, nullptr, nullptr, n, 256, 256, 2);
  g64(ws + h_off,  0, 256, nullptr, W2, 256, ws + y_off, 0, 256, b2, nullptr, nullptr, nullptr, n, 256, 256, 0);

  // scalar channel: out[n,0,:] = x_mid[n,0,:] + y[:, :128]
  out_scalar_kernel<<<(n * 128 + 255) / 256, 256, 0, stream>>>(xmid, ws + y_off, out, n);

  // gated vector channels: one block owns all 128 cols of its rows (BN=128) so
  // A-reads (x_mid) and C-writes (d_out, same memory) never cross blocks.
  {
    dim3 grid((3 * n + 31) / 32, 1);
    gemm_kernel<32,128,32,2,8><<<grid, 256, 0, stream>>>(
        xmid, 1, 0, nullptr, Wl, C_DIM, out, 1, 0,
        nullptr, nullptr, xmid, ws + y_off, 3 * n, C_DIM, C_DIM, 4);
  }
}

// Round 3
// 377.634 us; speedup vs baseline: 1.6370x; 1.6370x over previous
//
#include <hip/hip_runtime.h>
#include <math.h>

#define C_DIM 128
#define H_NUM 8
#define DH_NUM 16
#define NP_NUM 4
#define HD 128   // H*DH
#define PC 32    // H*NP

// ---------------- helpers ----------------
__device__ __forceinline__ float dot4f(float4 a, float4 b){
  return a.x*b.x + a.y*b.y + a.z*b.z + a.w*b.w;
}
__device__ __forceinline__ float4 scale4(float4 a, float s){
  return make_float4(a.x*s, a.y*s, a.z*s, a.w*s);
}
__device__ __forceinline__ float4 fma4(float4 acc, float p, float4 v){
  return make_float4(acc.x + p*v.x, acc.y + p*v.y, acc.z + p*v.z, acc.w + p*v.w);
}
__device__ __forceinline__ float sqdiff4(float4 a, float4 b){
  float dx = a.x - b.x, dy = a.y - b.y, dz = a.z - b.z, dw = a.w - b.w;
  return dx*dx + dy*dy + dz*dz + dw*dw;
}
__device__ __forceinline__ float gelu_exact(float v){
  return 0.5f * v * (1.0f + erff(v * 0.70710678118654752440f));
}
// row-offset modes: 0 -> r*ld ; 1 -> x-like (N,4,C) vector rows: (r/3)*512 + (r%3+1)*128
__device__ __forceinline__ size_t row_off(int mode, int r, int ld){
  if (mode == 0) return (size_t)r * (size_t)ld;
  int n3 = r / 3;
  int xd = r - n3 * 3;
  return (size_t)n3 * 512 + (size_t)(xd + 1) * 128;
}

#define RED4(v, off) { v.x += __shfl_xor(v.x, off); v.y += __shfl_xor(v.y, off); \
                       v.z += __shfl_xor(v.z, off); v.w += __shfl_xor(v.w, off); }

// ---------------- CSR build ----------------
__global__ void count_kernel(const int* __restrict__ ei, int* __restrict__ deg, int E){
  int e = blockIdx.x * blockDim.x + threadIdx.x;
  if (e < E) atomicAdd(&deg[ei[E + e]], 1);
}

__global__ __launch_bounds__(1024) void scan_kernel(const int* __restrict__ deg,
                                                    int* __restrict__ row_start, int n){
  __shared__ int sums[1024];
  int tid = threadIdx.x;
  int chunk = (n + 1023) >> 10;
  int beg = tid * chunk;
  int end = beg + chunk; if (end > n) end = n;
  int s = 0;
  for (int i = beg; i < end; ++i) s += deg[i];
  sums[tid] = s;
  __syncthreads();
  for (int off = 1; off < 1024; off <<= 1){
    int v = (tid >= off) ? sums[tid - off] : 0;
    __syncthreads();
    sums[tid] += v;
    __syncthreads();
  }
  int run = (tid > 0) ? sums[tid - 1] : 0;
  for (int i = beg; i < end; ++i){ row_start[i] = run; run += deg[i]; }
  if (tid == 1023) row_start[n] = sums[1023];
}

__global__ void fill_kernel(const int* __restrict__ ei, const int* __restrict__ row_start,
                            int* __restrict__ cursor, int* __restrict__ csr_src, int E){
  int e = blockIdx.x * blockDim.x + threadIdx.x;
  if (e >= E) return;
  int s = ei[e];
  int d = ei[E + e];
  int pos = atomicAdd(&cursor[d], 1);
  csr_src[row_start[d] + pos] = s;
}

// ---------------- weight packing: Wq|Wk|Wv -> [128,384], pts -> [128,96] ----
__global__ void pack_kernel(const float* __restrict__ Wq, const float* __restrict__ Wk,
                            const float* __restrict__ Wv, const float* __restrict__ Wqp,
                            const float* __restrict__ Wkp, const float* __restrict__ Wvp,
                            float* __restrict__ Bqkv, float* __restrict__ Bpts){
  int i = blockIdx.x * blockDim.x + threadIdx.x;
  if (i < 128 * 128){
    int k = i >> 7, c = i & 127;
    Bqkv[k * 384 + c]       = Wq[i];
    Bqkv[k * 384 + 128 + c] = Wk[i];
    Bqkv[k * 384 + 256 + c] = Wv[i];
  }
  if (i < 128 * 32){
    int k = i >> 5, c = i & 31;
    Bpts[k * 96 + c]      = Wqp[i];
    Bpts[k * 96 + 32 + c] = Wkp[i];
    Bpts[k * 96 + 64 + c] = Wvp[i];
  }
}

// ---------------- fp32 tiled GEMM, vectorized LDS, fused epilogues ----------
// epi: 0 none(+bias), 1 +rowadd[r], 2 gelu(acc+bias), 3 +bias+resid[coff+c],
//      4 gated residual: resid[coff+c] + acc*sigmoid(gate[(r/3)*256+128+c])
template<int BM, int BN, int BK>
__global__ __launch_bounds__(256) void gemm_kernel(
    const float* __restrict__ A, int amode, int lda, const float* __restrict__ subrow,
    const float* __restrict__ B, int ldb,
    float* __restrict__ C, int cmode, int ldc,
    const float* __restrict__ bias, const float* __restrict__ rowadd,
    const float* __restrict__ resid, const float* __restrict__ gate,
    int M, int K, int Nc, int epi)
{
  static_assert(BK == 32, "staging assumes BK==32");
  __shared__ float As[BK][BM + 4];   // +4 keeps rows 16B-aligned for b128 reads
  __shared__ float Bs[BK][BN + 4];
  constexpr int TM = 4, TN = 4;
  constexpr int TX = BN / TN, TY = BM / TM;
  static_assert(TX * TY == 256, "256-thread block");
  const int tid = threadIdx.x;
  const int tx = tid % TX;
  const int ty = tid / TX;
  const int rb = blockIdx.x * BM;
  const int cb = blockIdx.y * BN;

  float acc[TM][TN];
  #pragma unroll
  for (int u = 0; u < TM; ++u)
    #pragma unroll
    for (int v = 0; v < TN; ++v) acc[u][v] = 0.f;

  for (int k0 = 0; k0 < K; k0 += BK){
    // ---- stage A (transposed): BM*BK/4 float4 loads across 256 threads ----
    constexpr int AF4 = BM * BK / 4 / 256;
    #pragma unroll
    for (int i = 0; i < AF4; ++i){
      int fi = tid + i * 256;
      int r  = fi >> 3;          // 8 float4 per row (BK=32)
      int k4 = fi & 7;
      int row = rb + r;
      float4 val = make_float4(0.f, 0.f, 0.f, 0.f);
      if (row < M){
        val = *(const float4*)&A[row_off(amode, row, lda) + (size_t)(k0 + k4 * 4)];
        if (subrow){ float s = subrow[row]; val.x -= s; val.y -= s; val.z -= s; val.w -= s; }
      }
      As[k4 * 4 + 0][r] = val.x;
      As[k4 * 4 + 1][r] = val.y;
      As[k4 * 4 + 2][r] = val.z;
      As[k4 * 4 + 3][r] = val.w;
    }
    // ---- stage B (row-major): float4 straight through ----
    constexpr int BF4 = BK * BN / 4 / 256;
    #pragma unroll
    for (int i = 0; i < BF4; ++i){
      int fi = tid + i * 256;
      constexpr int C4 = BN / 4;
      int kk = fi / C4;
      int c4 = fi % C4;
      int col = cb + c4 * 4;
      float4 val = make_float4(0.f, 0.f, 0.f, 0.f);
      if (col < Nc) val = *(const float4*)&B[(size_t)(k0 + kk) * ldb + col];
      *(float4*)&Bs[kk][c4 * 4] = val;
    }
    __syncthreads();
    #pragma unroll
    for (int kk = 0; kk < BK; ++kk){
      float4 av = *(const float4*)&As[kk][ty * TM];
      float4 bv = *(const float4*)&Bs[kk][tx * TN];
      float a[TM] = {av.x, av.y, av.z, av.w};
      float b[TN] = {bv.x, bv.y, bv.z, bv.w};
      #pragma unroll
      for (int u = 0; u < TM; ++u)
        #pragma unroll
        for (int v = 0; v < TN; ++v) acc[u][v] += a[u] * b[v];
    }
    __syncthreads();
  }

  #pragma unroll
  for (int u = 0; u < TM; ++u){
    int r = rb + ty * TM + u;
    if (r >= M) continue;
    size_t coff = row_off(cmode, r, ldc);
    int c0 = cb + tx * TN;
    float4 val = make_float4(acc[u][0], acc[u][1], acc[u][2], acc[u][3]);
    if (bias){
      val.x += bias[c0]; val.y += bias[c0+1]; val.z += bias[c0+2]; val.w += bias[c0+3];
    }
    if (epi == 1){
      float ra = rowadd[r];
      val.x += ra; val.y += ra; val.z += ra; val.w += ra;
    } else if (epi == 2){
      val.x = gelu_exact(val.x); val.y = gelu_exact(val.y);
      val.z = gelu_exact(val.z); val.w = gelu_exact(val.w);
    } else if (epi == 3){
      const float4 rs = *(const float4*)&resid[coff + c0];
      val.x += rs.x; val.y += rs.y; val.z += rs.z; val.w += rs.w;
    } else if (epi == 4){
      const float4 rs = *(const float4*)&resid[coff + c0];
      const float4 gt = *(const float4*)&gate[(size_t)(r / 3) * 256 + 128 + c0];
      val.x = rs.x + val.x / (1.f + expf(-gt.x));
      val.y = rs.y + val.y / (1.f + expf(-gt.y));
      val.z = rs.z + val.z / (1.f + expf(-gt.z));
      val.w = rs.w + val.w / (1.f + expf(-gt.w));
    }
    if (c0 + 3 < Nc){
      *(float4*)&C[coff + c0] = val;
    } else {
      float vv[4] = {val.x, val.y, val.z, val.w};
      for (int v = 0; v < TN; ++v) if (c0 + v < Nc) C[coff + c0 + v] = vv[v];
    }
  }
}

// ---------------- per-node online-softmax attention over CSR ----------------
// One wave (64 lanes) per node: 8 edge-slots (g) x 8 heads (h).
// qkv: [n][384] (q|k|v), pts: [3n][96] (qp|kp|vp)
__global__ __launch_bounds__(64) void attn_kernel(
    const float* __restrict__ qkv, const float* __restrict__ pts,
    const float* __restrict__ gamma,
    const int* __restrict__ row_start, const int* __restrict__ csr_src,
    float* __restrict__ agg_s, float* __restrict__ agg_p, int n)
{
  const int node = blockIdx.x;
  if (node >= n) return;
  const int lane = threadIdx.x;
  const int g = lane >> 3;
  const int h = lane & 7;

  const float4* q4 = (const float4*)(qkv + (size_t)node * 384 + h * DH_NUM);
  const float4 qa = q4[0], qb = q4[1], qc = q4[2], qd = q4[3];
  const float4 qp0 = *(const float4*)(pts + ((size_t)node * 3 + 0) * 96 + h * 4);
  const float4 qp1 = *(const float4*)(pts + ((size_t)node * 3 + 1) * 96 + h * 4);
  const float4 qp2 = *(const float4*)(pts + ((size_t)node * 3 + 2) * 96 + h * 4);
  const float c05 = 0.5f * log1pf(expf(gamma[h]));

  const int e0 = row_start[node], e1 = row_start[node + 1];

  float m_run = -INFINITY;
  float zacc = 0.f;
  float4 as0 = make_float4(0,0,0,0), as1 = as0, as2 = as0, as3 = as0;
  float4 ap0 = as0, ap1 = as0, ap2 = as0;

  for (int base = e0; base < e1; base += 8){
    const int e = base + g;
    const bool valid = (e < e1);
    const int src = valid ? csr_src[e] : 0;

    const float4* k4 = (const float4*)(qkv + (size_t)src * 384 + 128 + h * DH_NUM);
    float dot = dot4f(qa, k4[0]) + dot4f(qb, k4[1]) + dot4f(qc, k4[2]) + dot4f(qd, k4[3]);
    const float4 kp0 = *(const float4*)(pts + ((size_t)src * 3 + 0) * 96 + 32 + h * 4);
    const float4 kp1 = *(const float4*)(pts + ((size_t)src * 3 + 1) * 96 + 32 + h * 4);
    const float4 kp2 = *(const float4*)(pts + ((size_t)src * 3 + 2) * 96 + 32 + h * 4);
    float pd = sqdiff4(qp0, kp0) + sqdiff4(qp1, kp1) + sqdiff4(qp2, kp2);
    float logit = valid ? (dot * 0.25f - c05 * pd) : -INFINITY;

    // tile max across the 8 edge slots (lanes differing in bits 3..5, same head)
    float tmax = logit;
    tmax = fmaxf(tmax, __shfl_xor(tmax, 8));
    tmax = fmaxf(tmax, __shfl_xor(tmax, 16));
    tmax = fmaxf(tmax, __shfl_xor(tmax, 32));
    float m_new = fmaxf(m_run, tmax);
    float sc = expf(m_run - m_new);    // exp(-inf)=0 on first iter
    float pe = valid ? expf(logit - m_new) : 0.f;
    m_run = m_new;

    const float4* v4 = (const float4*)(qkv + (size_t)src * 384 + 256 + h * DH_NUM);
    const float4 vv0 = v4[0], vv1 = v4[1], vv2 = v4[2], vv3 = v4[3];
    const float4 vp0 = *(const float4*)(pts + ((size_t)src * 3 + 0) * 96 + 64 + h * 4);
    const float4 vp1 = *(const float4*)(pts + ((size_t)src * 3 + 1) * 96 + 64 + h * 4);
    const float4 vp2 = *(const float4*)(pts + ((size_t)src * 3 + 2) * 96 + 64 + h * 4);

    zacc = zacc * sc + pe;
    as0 = fma4(scale4(as0, sc), pe, vv0);
    as1 = fma4(scale4(as1, sc), pe, vv1);
    as2 = fma4(scale4(as2, sc), pe, vv2);
    as3 = fma4(scale4(as3, sc), pe, vv3);
    ap0 = fma4(scale4(ap0, sc), pe, vp0);
    ap1 = fma4(scale4(ap1, sc), pe, vp1);
    ap2 = fma4(scale4(ap2, sc), pe, vp2);
  }

  // reduce across the 8 edge slots (all lanes of a head share identical m_run)
  for (int off = 8; off < 64; off <<= 1){
    zacc += __shfl_xor(zacc, off);
    RED4(as0, off); RED4(as1, off); RED4(as2, off); RED4(as3, off);
    RED4(ap0, off); RED4(ap1, off); RED4(ap2, off);
  }
  float inv = 1.f / (zacc + 1e-9f);
  if (g == 0){
    float4* o = (float4*)(agg_s + (size_t)node * HD + h * DH_NUM);
    o[0] = scale4(as0, inv); o[1] = scale4(as1, inv);
    o[2] = scale4(as2, inv); o[3] = scale4(as3, inv);
    *(float4*)(agg_p + ((size_t)node * 3 + 0) * PC + h * 4) = scale4(ap0, inv);
    *(float4*)(agg_p + ((size_t)node * 3 + 1) * PC + h * 4) = scale4(ap1, inv);
    *(float4*)(agg_p + ((size_t)node * 3 + 2) * PC + h * 4) = scale4(ap2, inv);
  }
}

// ---------------- small glue kernels ----------------
__global__ void norm_kernel(const float* __restrict__ xm, float* __restrict__ x1, int n){
  int i = blockIdx.x * blockDim.x + threadIdx.x;
  if (i >= n * 128) return;
  int node = i >> 7, c = i & 127;
  const float* b = xm + (size_t)node * 512;
  float v1 = b[128 + c], v2 = b[256 + c], v3 = b[384 + c];
  x1[(size_t)node * 256 + c] = b[c];
  x1[(size_t)node * 256 + 128 + c] = sqrtf(v1*v1 + v2*v2 + v3*v3 + 1e-4f);
}

__global__ void out_scalar_kernel(const float* __restrict__ xm, const float* __restrict__ y,
                                  float* __restrict__ out, int n){
  int i = blockIdx.x * blockDim.x + threadIdx.x;
  if (i >= n * 128) return;
  int node = i >> 7, c = i & 127;
  out[(size_t)node * 512 + c] = xm[(size_t)node * 512 + c] + y[(size_t)node * 256 + c];
}

// ---------------- launch ----------------
extern "C" void kernel_launch(void* const* d_in, const int* in_sizes, int n_in,
                              void* d_out, int out_size, void* d_ws, size_t ws_size,
                              hipStream_t stream)
{
  const float* x      = (const float*)d_in[0];
  const int*   ei     = (const int*)d_in[1];
  const float* t      = (const float*)d_in[2];
  const float* Wq     = (const float*)d_in[3];
  const float* Wk     = (const float*)d_in[4];
  const float* Wv     = (const float*)d_in[5];
  const float* Wq_pts = (const float*)d_in[6];
  const float* Wk_pts = (const float*)d_in[7];
  const float* Wv_pts = (const float*)d_in[8];
  const float* gamma  = (const float*)d_in[9];
  const float* Wo_s   = (const float*)d_in[10];
  const float* bo_s   = (const float*)d_in[11];
  const float* Wo_pts = (const float*)d_in[12];
  const float* W1     = (const float*)d_in[13];
  const float* b1     = (const float*)d_in[14];
  const float* W2     = (const float*)d_in[15];
  const float* b2     = (const float*)d_in[16];
  const float* Wl     = (const float*)d_in[17];
  float* out = (float*)d_out;

  const int n = in_sizes[0] / 512;
  const int E = in_sizes[1] / 2;

  float* ws = (float*)d_ws;
  // float regions (elements)
  size_t sproj_off = 0;                               // [n][384]  q|k|v
  size_t pproj_off = (size_t)n * 384;                 // [3n][96]  qp|kp|vp
  size_t aggs_off  = (size_t)n * 672;                 // [n][128]
  size_t aggp_off  = (size_t)n * 800;                 // [3n][32]
  size_t x1_off    = (size_t)n * 896;                 // [n][256]
  size_t f_end     = (size_t)n * 1152;
  // MLP buffers reuse the dead projection region ([0, n*672))
  size_t h_off = 0;                                   // [n][256]
  size_t y_off = (size_t)n * 256;                     // [n][256]

  int* ibase     = (int*)(ws + f_end);
  int* deg       = ibase;
  int* cursor    = deg + n;
  int* row_start = cursor + n;
  int* csr_src   = row_start + (n + 1);
  // packed weights after int region (align up to 4 floats)
  size_t int_end_f = f_end + ((size_t)(2 * n + n + 1 + E) + 3) / 4 * 4 + 4;
  float* Bqkv = ws + int_end_f;                       // [128][384]
  float* Bpts = Bqkv + 128 * 384;                     // [128][96]

  // CSR build + weight pack
  hipMemsetAsync(deg, 0, sizeof(int) * (size_t)(2 * n), stream);
  count_kernel<<<(E + 255) / 256, 256, 0, stream>>>(ei, deg, E);
  pack_kernel<<<64, 256, 0, stream>>>(Wq, Wk, Wv, Wq_pts, Wk_pts, Wv_pts, Bqkv, Bpts);
  scan_kernel<<<1, 1024, 0, stream>>>(deg, row_start, n);
  fill_kernel<<<(E + 255) / 256, 256, 0, stream>>>(ei, row_start, cursor, csr_src, E);

  // s-projection: [n,128] @ [128,384] -> qkv
  {
    dim3 grid((n + 63) / 64, 6);
    gemm_kernel<64,64,32><<<grid, 256, 0, stream>>>(
        x, 0, 512, nullptr, Bqkv, 384, ws + sproj_off, 0, 384,
        nullptr, nullptr, nullptr, nullptr, n, 128, 384, 0);
  }
  // pts-projection: [3n,128] @ [128,96] + t -> pts
  {
    dim3 grid((3 * n + 127) / 128, 3);
    gemm_kernel<128,32,32><<<grid, 256, 0, stream>>>(
        x, 1, 0, nullptr, Bpts, 96, ws + pproj_off, 0, 96,
        nullptr, t, nullptr, nullptr, 3 * n, 128, 96, 1);
  }

  // attention
  attn_kernel<<<n, 64, 0, stream>>>(ws + sproj_off, ws + pproj_off,
                                    gamma, row_start, csr_src,
                                    ws + aggs_off, ws + aggp_off, n);

  // x_mid lives in d_out (residual-add fused)
  float* xmid = out;
  {
    dim3 grid((n + 63) / 64, 2);
    gemm_kernel<64,64,32><<<grid, 256, 0, stream>>>(
        ws + aggs_off, 0, HD, nullptr, Wo_s, C_DIM, xmid, 0, 512,
        bo_s, nullptr, x, nullptr, n, HD, C_DIM, 3);
  }
  {
    dim3 grid((3 * n + 63) / 64, 2);
    gemm_kernel<64,64,32><<<grid, 256, 0, stream>>>(
        ws + aggp_off, 0, PC, t, Wo_pts, C_DIM, xmid, 1, 0,
        nullptr, nullptr, x, nullptr, 3 * n, PC, C_DIM, 3);
  }

  // norm -> x1
  norm_kernel<<<(n * 128 + 255) / 256, 256, 0, stream>>>(xmid, ws + x1_off, n);

  // MLP
  {
    dim3 grid((n + 63) / 64, 4);
    gemm_kernel<64,64,32><<<grid, 256, 0, stream>>>(
        ws + x1_off, 0, 256, nullptr, W1, 256, ws + h_off, 0, 256,
        b1, nullptr, nullptr, nullptr, n, 256, 256, 2);
    gemm_kernel<64,64,32><<<grid, 256, 0, stream>>>(
        ws + h_off, 0, 256, nullptr, W2, 256, ws + y_off, 0, 256,
        b2, nullptr, nullptr, nullptr, n, 256, 256, 0);
  }

  // scalar channel: out[n,0,:] = x_mid[n,0,:] + y[:, :128]
  out_scalar_kernel<<<(n * 128 + 255) / 256, 256, 0, stream>>>(xmid, ws + y_off, out, n);

  // gated vector channels: BN=128 -> one block owns all cols of its rows, so
  // A-reads (x_mid) and C-writes (d_out, same memory) never cross blocks.
  {
    dim3 grid((3 * n + 31) / 32, 1);
    gemm_kernel<32,128,32><<<grid, 256, 0, stream>>>(
        xmid, 1, 0, nullptr, Wl, C_DIM, out, 1, 0,
        nullptr, nullptr, xmid, ws + y_off, 3 * n, C_DIM, C_DIM, 4);
  }
}